// Round 5
// baseline (148.874 us; speedup 1.0000x reference)
//
#include <hip/hip_runtime.h>
#include <math.h>

#define Bn 8
#define Qn 20
#define Pn 12
#define Nn 4096
#define Gn 2048
#define Mn 1280   /* Q*FACTOR */
#define Fn 64
#define KNB 7     /* K_NEIGHBORS - 1 */
#define DONE_TARGET 464  /* 8 hungarian + 40 repulsion + 160 chamferA + 256 chamferB */

// ---------------- workspace layout (32-bit words) ----------------
// cham  : 0      (1920)  (B,Q,P)
// ns    : 1920   (1920)
// dd    : 3840   (1920)
// cost  : 5760   (1920)
// cnt   : 7680   (96)
// acc   : 7776   (6)     0 cls, 1 param, 2 pvd, 3 rep, 4 ch1, 5 ch2
// costc : 7784   (8)     per-batch cost-block counters (target 20)
// done  : 7792   (1)     global contributor counter (target 464)
//
// Cross-block data discipline (single dispatch, cross-XCD): every communicated
// value moves via atomic RMW (resolves at device coherence point) + __threadfence
// for ordering. Chamfer now has ZERO cross-block traffic (R4's 327K atomicMin
// RMWs were the 60us regression).
__device__ __forceinline__ float aread(float* p) { return atomicAdd(p, 0.0f); }
__device__ __forceinline__ void awrite(float* p, float v) { atomicExch(p, v); }

__device__ __forceinline__ void contribute(float* acc, int* done, float* out) {
    __threadfence();
    int old = atomicAdd(done, 1);
    if (old == DONE_TARGET - 1) {
        __threadfence();
        float a0 = aread(&acc[0]);
        float a1 = aread(&acc[1]);
        float a2 = aread(&acc[2]);
        float a3 = aread(&acc[3]);
        float a4 = aread(&acc[4]);
        float a5 = aread(&acc[5]);
        out[0] = a0 + 0.5f * a1 + 20.f * a2 + a3 + a4 + a5;
    }
}

__global__ void init_kernel(unsigned int* wsu) {
    if (threadIdx.x < 20) wsu[7776 + threadIdx.x] = 0u;
}

// ============ mega: cost(160) + repulsion(40) + chamferA(160) + chamferB(256) ============
__global__ void mega_kernel(const float* __restrict__ pred_logits,
                            const float* __restrict__ pred_normals,
                            const float* __restrict__ pred_distances,
                            const float* __restrict__ gt_normals,
                            const float* __restrict__ gt_distances,
                            const float* __restrict__ points,
                            const int*   __restrict__ gt_masks,
                            const float* __restrict__ recon,
                            const float* __restrict__ gt,
                            float* __restrict__ ws, float* __restrict__ out) {
    __shared__ float smem[2 * Pn * 256];
    __shared__ double hsm[Pn * Qn];
    __shared__ int sflag;
    const int blk = blockIdx.x;
    const int tid = threadIdx.x;

    float* cham = ws;
    float* ns   = ws + 1920;
    float* dd   = ws + 3840;
    float* cost = ws + 5760;
    float* cnt  = ws + 7680;
    float* acc  = ws + 7776;
    int*   costc = (int*)(ws + 7784);
    int*   done  = (int*)(ws + 7792);

    if (blk < 160) {
        // ---------------- cost path: one block per (b,q) ----------------
        const int b = blk / Qn, q = blk % Qn;
        const float nx = pred_normals[(b * Qn + q) * 3 + 0];
        const float ny = pred_normals[(b * Qn + q) * 3 + 1];
        const float nz = pred_normals[(b * Qn + q) * 3 + 2];
        const float dq = pred_distances[b * Qn + q];

        float accs[Pn], accw[Pn];
#pragma unroll
        for (int p = 0; p < Pn; ++p) { accs[p] = 0.f; accw[p] = 0.f; }

        const float* ptb = points + (size_t)b * Nn * 3;
        const int*   mb  = gt_masks + (size_t)b * Pn * Nn;

        for (int n = tid; n < Nn; n += 256) {
            float px = ptb[n * 3 + 0], py = ptb[n * 3 + 1], pz = ptb[n * 3 + 2];
            float pp = fabsf(px * nx + py * ny + pz * nz - dq);
#pragma unroll
            for (int p = 0; p < Pn; ++p) {
                float m = (float)mb[(size_t)p * Nn + n];
                accs[p] += pp * m;
                accw[p] += m;
            }
        }
#pragma unroll
        for (int p = 0; p < Pn; ++p) {
            smem[p * 256 + tid] = accs[p];
            smem[(p + Pn) * 256 + tid] = accw[p];
        }
        __syncthreads();
        for (int off = 128; off > 0; off >>= 1) {
            if (tid < off) {
#pragma unroll
                for (int r = 0; r < 2 * Pn; ++r) smem[r * 256 + tid] += smem[r * 256 + tid + off];
            }
            __syncthreads();
        }
        if (tid < Pn) {
            const int p = tid;
            float c  = smem[(p + Pn) * 256];
            float cv = smem[p * 256] / fmaxf(c, 1.f);
            float gnx = gt_normals[(b * Pn + p) * 3 + 0];
            float gny = gt_normals[(b * Pn + p) * 3 + 1];
            float gnz = gt_normals[(b * Pn + p) * 3 + 2];
            float nsim = 1.f - fabsf(nx * gnx + ny * gny + nz * gnz);
            float ddv  = fabsf(dq - gt_distances[b * Pn + p]);
            int idx = (b * Qn + q) * Pn + p;
            awrite(&cham[idx], cv);
            awrite(&ns[idx],   nsim);
            awrite(&dd[idx],   ddv);
            awrite(&cost[idx], nsim + 0.5f * ddv + 5.f * ((c > 0.f) ? cv : 1.f));
            if (q == 0) awrite(&cnt[b * Pn + p], c);
        }
        __syncthreads();
        if (tid == 0) {
            __threadfence();
            int old = atomicAdd(&costc[b], 1);
            sflag = (old == Qn - 1) ? 1 : 0;
        }
        __syncthreads();
        if (!sflag) return;
        if (tid >= 64) return;
        __threadfence();

        // ---- promoted (last arriver for batch b): wave-parallel transposed JV ----
        // Equivalent to reference's pad-to-square 20x20 (proven absmax 0.0 in R2-R4).
        const int t = tid;
        for (int k = t; k < Qn * Pn; k += 64)
            hsm[(k % Pn) * Qn + (k / Pn)] = (double)aread(&cost[b * Qn * Pn + k]);

        const int col = t;
        const bool isCol = (col >= 1 && col <= Qn);
        double v = 0.0, u = 0.0, minv = 0.0;
        int way = 0, p = 0;

        for (int i = 1; i <= Pn; ++i) {
            const int p0 = i;
            minv = 1e18;
            bool used = false;
            bool rowInPath = false;
            int j0 = 0;
            while (true) {
                if (col == j0) used = true;
                int i0 = (j0 == 0) ? p0 : __shfl(p, j0);
                if (t == i0) rowInPath = true;
                double u_i0 = __shfl(u, i0);
                double mv = 1e18;
                if (isCol && !used) {
                    double cur = hsm[(i0 - 1) * Qn + (col - 1)] - u_i0 - v;
                    if (cur < minv) { minv = cur; way = j0; }
                    mv = minv;
                }
                double bv = mv; int bj = col;
#pragma unroll
                for (int off = 16; off > 0; off >>= 1) {
                    double ov = __shfl_down(bv, off);
                    int    oj = __shfl_down(bj, off);
                    if (ov < bv) { bv = ov; bj = oj; }
                }
                double delta = __shfl(bv, 0);
                int    j1    = __shfl(bj, 0);
                if (used || col == 0) v -= delta;
                else if (isCol)       minv -= delta;
                if (rowInPath)        u += delta;
                j0 = j1;
                int pj0 = __shfl(p, j0);
                if (pj0 == 0) break;
            }
            while (j0 != 0) {
                int wj = __shfl(way, j0);
                int pw = (wj == 0) ? p0 : __shfl(p, wj);
                if (col == j0) p = pw;
                j0 = wj;
            }
        }

        // ---- fused small losses for batch b ----
        float cls = 0.f, par = 0.f, pvd = 0.f;
        if (isCol) {
            float x = pred_logits[b * Qn + (col - 1)];
            float tgt = (p > 0) ? 1.f : 0.f;
            cls = fmaxf(x, 0.f) - x * tgt + log1pf(expf(-fabsf(x)));
            if (p > 0) {
                int idx = (b * Qn + (col - 1)) * Pn + (p - 1);
                par = aread(&ns[idx]) + aread(&dd[idx]);
                pvd = (aread(&cnt[b * Pn + (p - 1)]) > 0.f) ? aread(&cham[idx]) : 0.f;
            }
        }
        for (int off = 32; off > 0; off >>= 1) {
            cls += __shfl_down(cls, off);
            par += __shfl_down(par, off);
            pvd += __shfl_down(pvd, off);
        }
        if (t == 0) {
            atomicAdd(&acc[0], cls / (float)(Bn * Qn));
            atomicAdd(&acc[1], par / (float)(Bn * Pn));
            atomicAdd(&acc[2], pvd / (float)(Bn * Pn));
            contribute(acc, done, out);
        }
    } else if (blk < 200) {
        // ---------------- repulsion: 4 waves per block, one 64-pt group per wave ----------------
        const int wave = tid >> 6, lane = tid & 63;
        const int g = (blk - 160) * 4 + wave;
        float* xs = smem + wave * 192;
        float* ys = xs + 64;
        float* zs = xs + 128;
        const float* base = recon + (size_t)g * Fn * 3;
        xs[lane] = base[lane * 3 + 0];
        ys[lane] = base[lane * 3 + 1];
        zs[lane] = base[lane * 3 + 2];
        // wave-local LDS region: wave-synchronous, no barrier needed before reads
        float best[KNB];
#pragma unroll
        for (int k = 0; k < KNB; ++k) best[k] = 3.4e38f;
        const float xi = xs[lane], yi = ys[lane], zi = zs[lane];
        for (int j = 0; j < Fn; ++j) {
            if (j == lane) continue;
            float dx = xi - xs[j], dy = yi - ys[j], dz = zi - zs[j];
            float d2 = dx * dx + dy * dy + dz * dz;
            if (d2 < best[KNB - 1]) {
                int k = KNB - 1;
                while (k > 0 && best[k - 1] > d2) { best[k] = best[k - 1]; --k; }
                best[k] = d2;
            }
        }
        float sum = 0.f;
#pragma unroll
        for (int k = 0; k < KNB; ++k) {
            float dn = fmaxf(best[k], 1e-12f);
            float w  = expf(-dn / (0.03f * 0.03f));
            sum += (0.07f - sqrtf(dn)) * w;
        }
        for (int off = 32; off > 0; off >>= 1) sum += __shfl_down(sum, off);
        if (lane == 0) smem[1000 + wave] = fmaxf(sum / (float)(Fn * KNB), 0.f);
        __syncthreads();
        if (tid == 0) {
            float total = (smem[1000] + smem[1001] + smem[1002] + smem[1003]) / (float)(Bn * Qn);
            atomicAdd(&acc[3], total);
            contribute(acc, done, out);
        }
    } else {
        // -------- chamfer: block owns 64 outer points, scans FULL opposite cloud --------
        // lane o = tid&63 -> outer point; wave s = tid>>6 -> inner quarter.
        // Inner loads are wave-broadcast (all lanes same address) -> single request.
        // No cross-block communication at all.
        const int o = tid & 63, s = tid >> 6;
        int a = blk - 200;
        const bool isA = (a < 160);
        int idx, b, innerN;
        const float* inner;
        float x, y, z;
        if (isA) {
            idx = a * 64 + o;                  // over B*M (64 | 1280: no straddle)
            b = idx / Mn;
            x = recon[idx * 3 + 0]; y = recon[idx * 3 + 1]; z = recon[idx * 3 + 2];
            inner = gt + (size_t)b * Gn * 3;
            innerN = Gn;
        } else {
            a -= 160;
            idx = a * 64 + o;                  // over B*G (64 | 2048: no straddle)
            b = idx / Gn;
            x = gt[idx * 3 + 0]; y = gt[idx * 3 + 1]; z = gt[idx * 3 + 2];
            inner = recon + (size_t)b * Mn * 3;
            innerN = Mn;
        }
        const int chunk = innerN >> 2;
        const int j0 = s * chunk, j1 = j0 + chunk;
        float m1 = 3.4e38f, m2 = 3.4e38f;
        for (int j = j0; j < j1; ++j) {
            float dx = x - inner[j * 3 + 0];
            float dy = y - inner[j * 3 + 1];
            float dz = z - inner[j * 3 + 2];
            float d1 = fabsf(dx) + fabsf(dy) + fabsf(dz);
            float d2 = dx * dx + dy * dy + dz * dz;
            m1 = fminf(m1, d1); m2 = fminf(m2, d2);
        }
        smem[tid] = m1; smem[256 + tid] = m2;
        __syncthreads();
        if (tid < 64) {
            float f1 = fminf(fminf(smem[o], smem[64 + o]), fminf(smem[128 + o], smem[192 + o]));
            float f2 = fminf(fminf(smem[256 + o], smem[320 + o]), fminf(smem[384 + o], smem[448 + o]));
            for (int off = 32; off > 0; off >>= 1) {
                f1 += __shfl_down(f1, off);
                f2 += __shfl_down(f2, off);
            }
            if (o == 0) {
                float scale = isA ? (0.5f / (float)(Bn * Mn)) : (0.5f / (float)(Bn * Gn));
                atomicAdd(&acc[4], f1 * scale);
                atomicAdd(&acc[5], f2 * scale);
                contribute(acc, done, out);
            }
        }
    }
}

extern "C" void kernel_launch(void* const* d_in, const int* in_sizes, int n_in,
                              void* d_out, int out_size, void* d_ws, size_t ws_size,
                              hipStream_t stream) {
    const float* pred_logits    = (const float*)d_in[0];
    const float* pred_normals   = (const float*)d_in[1];
    const float* pred_distances = (const float*)d_in[2];
    const float* gt_normals     = (const float*)d_in[3];
    const float* gt_distances   = (const float*)d_in[4];
    const int*   gt_masks       = (const int*)d_in[5];
    const float* points         = (const float*)d_in[6];
    const float* recon          = (const float*)d_in[7];
    const float* gt             = (const float*)d_in[8];
    // d_in[9] (gt_index) is unused by the reference.

    init_kernel<<<1, 64, 0, stream>>>((unsigned int*)d_ws);
    mega_kernel<<<616, 256, 0, stream>>>(pred_logits, pred_normals, pred_distances,
                                         gt_normals, gt_distances, points, gt_masks,
                                         recon, gt, (float*)d_ws, (float*)d_out);
}

// Round 7
// 133.435 us; speedup vs baseline: 1.1157x; 1.1157x over previous
//
#include <hip/hip_runtime.h>
#include <math.h>

#define Bn 8
#define Qn 20
#define Pn 12
#define Nn 4096
#define Gn 2048
#define Mn 1280   /* Q*FACTOR */
#define Fn 64
#define KNB 7     /* K_NEIGHBORS - 1 */
#define SA 8      /* gt splits for chamfer A (2048/256)  */
#define SB 5      /* recon splits for chamfer B (1280/256) */
#define DONE_TARGET 113  /* 8 hungarian + 104 chamfer reducers + 1 repulsion reducer */

// ---------------- workspace layout (32-bit words) ----------------
// cham  : 0      (1920)   (B,Q,P)
// ns    : 1920   (1920)
// dd    : 3840   (1920)
// cost  : 5760   (1920)
// cnt   : 7680   (96)
// acc   : 7776   (6)      0 cls, 1 param, 2 pvd, 3 rep, 4 ch1, 5 ch2
// done  : 7782   (1)      finale contributor counter
// rep   : 7808   (160)    per-group repulsion partials
// pmA1  : 8192   (81920)  chamfer A partial mins (SA, B*M)   <-- R6 bug: was sized 10240,
// pmA2  : 90112  (81920)      slices overlapped pmA2. R3 offsets restored.
// pmB1  : 172032 (81920)  (SB, B*G)
// pmB2  : 253952 (81920)  .. 335872
//
// Design (R5/R6 post-mortem): per-block __threadfence + far-RMW promotion costs
// ~20us (FETCH 9MB invalidate refetches). Plain-store K1; kernel boundary gives
// coherence; tiny 113-block finale with counter-based finalization.

__device__ __forceinline__ float aread(float* p) { return atomicAdd(p, 0.0f); }

__device__ __forceinline__ void contribute(float* acc, int* done, float* out) {
    __threadfence();
    int old = atomicAdd(done, 1);
    if (old == DONE_TARGET - 1) {
        __threadfence();
        float a0 = aread(&acc[0]);
        float a1 = aread(&acc[1]);
        float a2 = aread(&acc[2]);
        float a3 = aread(&acc[3]);
        float a4 = aread(&acc[4]);
        float a5 = aread(&acc[5]);
        out[0] = a0 + 0.5f * a1 + 20.f * a2 + a3 + a4 + a5;
    }
}

// ============ K1: cost (160) + repulsion (40) + chamfer partials (640) ============
// Plain stores only; no fences; block 0 zeroes acc+done (visible at kernel boundary).
__global__ void mega1_kernel(const float* __restrict__ pred_normals,
                             const float* __restrict__ pred_distances,
                             const float* __restrict__ gt_normals,
                             const float* __restrict__ gt_distances,
                             const float* __restrict__ points,
                             const int*   __restrict__ gt_masks,
                             const float* __restrict__ recon,
                             const float* __restrict__ gt,
                             float* __restrict__ ws) {
    __shared__ float smem[2 * Pn * 256];
    const int blk = blockIdx.x;
    const int tid = threadIdx.x;

    float* cham = ws;
    float* ns   = ws + 1920;
    float* dd   = ws + 3840;
    float* cost = ws + 5760;
    float* cnt  = ws + 7680;
    float* acc  = ws + 7776;            // words 7776..7783 incl. done @7782
    float* rep_part = ws + 7808;
    float* pmA1 = ws + 8192;
    float* pmA2 = ws + 90112;
    float* pmB1 = ws + 172032;
    float* pmB2 = ws + 253952;

    if (blk < 160) {
        // ---- cost path: one block per (b,q) ----
        if (blk == 0 && tid < 8) acc[tid] = 0.f;   // acc[0..5] + done + pad
        const int b = blk / Qn, q = blk % Qn;
        const float nx = pred_normals[(b * Qn + q) * 3 + 0];
        const float ny = pred_normals[(b * Qn + q) * 3 + 1];
        const float nz = pred_normals[(b * Qn + q) * 3 + 2];
        const float dq = pred_distances[b * Qn + q];

        float accs[Pn], accw[Pn];
#pragma unroll
        for (int p = 0; p < Pn; ++p) { accs[p] = 0.f; accw[p] = 0.f; }

        const float* ptb = points + (size_t)b * Nn * 3;
        const int*   mb  = gt_masks + (size_t)b * Pn * Nn;

        for (int n = tid; n < Nn; n += 256) {
            float px = ptb[n * 3 + 0], py = ptb[n * 3 + 1], pz = ptb[n * 3 + 2];
            float pp = fabsf(px * nx + py * ny + pz * nz - dq);
#pragma unroll
            for (int p = 0; p < Pn; ++p) {
                float m = (float)mb[(size_t)p * Nn + n];
                accs[p] += pp * m;
                accw[p] += m;
            }
        }
#pragma unroll
        for (int p = 0; p < Pn; ++p) {
            smem[p * 256 + tid] = accs[p];
            smem[(p + Pn) * 256 + tid] = accw[p];
        }
        __syncthreads();
        for (int off = 128; off > 0; off >>= 1) {
            if (tid < off) {
#pragma unroll
                for (int r = 0; r < 2 * Pn; ++r) smem[r * 256 + tid] += smem[r * 256 + tid + off];
            }
            __syncthreads();
        }
        if (tid < Pn) {
            const int p = tid;
            float c  = smem[(p + Pn) * 256];
            float cv = smem[p * 256] / fmaxf(c, 1.f);
            float gnx = gt_normals[(b * Pn + p) * 3 + 0];
            float gny = gt_normals[(b * Pn + p) * 3 + 1];
            float gnz = gt_normals[(b * Pn + p) * 3 + 2];
            float nsim = 1.f - fabsf(nx * gnx + ny * gny + nz * gnz);
            float ddv  = fabsf(dq - gt_distances[b * Pn + p]);
            int idx = (b * Qn + q) * Pn + p;
            cham[idx] = cv;
            ns[idx]   = nsim;
            dd[idx]   = ddv;
            cost[idx] = nsim + 0.5f * ddv + 5.f * ((c > 0.f) ? cv : 1.f);
            if (q == 0) cnt[b * Pn + p] = c;
        }
    } else if (blk < 200) {
        // ---- repulsion: 4 waves per block, one (b,q) 64-pt group per wave ----
        const int wave = tid >> 6, lane = tid & 63;
        const int g = (blk - 160) * 4 + wave;
        float* xs = smem + wave * 192;
        float* ys = xs + 64;
        float* zs = xs + 128;
        const float* base = recon + (size_t)g * Fn * 3;
        xs[lane] = base[lane * 3 + 0];
        ys[lane] = base[lane * 3 + 1];
        zs[lane] = base[lane * 3 + 2];
        // wave-local LDS region: wave-synchronous access
        float best[KNB];
#pragma unroll
        for (int k = 0; k < KNB; ++k) best[k] = 3.4e38f;
        const float xi = xs[lane], yi = ys[lane], zi = zs[lane];
        for (int j = 0; j < Fn; ++j) {
            if (j == lane) continue;
            float dx = xi - xs[j], dy = yi - ys[j], dz = zi - zs[j];
            float d2 = dx * dx + dy * dy + dz * dz;
            if (d2 < best[KNB - 1]) {
                int k = KNB - 1;
                while (k > 0 && best[k - 1] > d2) { best[k] = best[k - 1]; --k; }
                best[k] = d2;
            }
        }
        float sum = 0.f;
#pragma unroll
        for (int k = 0; k < KNB; ++k) {
            float dn = fmaxf(best[k], 1e-12f);
            float w  = expf(-dn / (0.03f * 0.03f));
            sum += (0.07f - sqrtf(dn)) * w;
        }
        for (int off = 32; off > 0; off >>= 1) sum += __shfl_down(sum, off);
        if (lane == 0) rep_part[g] = fmaxf(sum / (float)(Fn * KNB), 0.f);
    } else {
        // ---- chamfer partial: LDS-tiled 256-pt inner chunk (R3-proven) ----
        int cblk = blk - 200;
        float* tx = smem;
        float* ty = smem + 256;
        float* tz = smem + 512;
        float x, y, z;
        const float* inner;
        float *o1, *o2;
        int idx;
        if (cblk < 40 * SA) {
            int s = cblk % SA, ob = cblk / SA;
            idx = ob * 256 + tid;                 // over B*M
            int b = idx / Mn;
            x = recon[idx * 3 + 0]; y = recon[idx * 3 + 1]; z = recon[idx * 3 + 2];
            inner = gt + ((size_t)b * Gn + s * 256) * 3;
            o1 = pmA1 + s * (Bn * Mn); o2 = pmA2 + s * (Bn * Mn);
        } else {
            cblk -= 40 * SA;
            int s = cblk % SB, ob = cblk / SB;
            idx = ob * 256 + tid;                 // over B*G
            int b = idx / Gn;
            x = gt[idx * 3 + 0]; y = gt[idx * 3 + 1]; z = gt[idx * 3 + 2];
            inner = recon + ((size_t)b * Mn + s * 256) * 3;
            o1 = pmB1 + s * (Bn * Gn); o2 = pmB2 + s * (Bn * Gn);
        }
        tx[tid] = inner[tid * 3 + 0];
        ty[tid] = inner[tid * 3 + 1];
        tz[tid] = inner[tid * 3 + 2];
        __syncthreads();
        float m1 = 3.4e38f, m2 = 3.4e38f;
        for (int j = 0; j < 256; ++j) {
            float dx = x - tx[j], dy = y - ty[j], dz = z - tz[j];
            float d1 = fabsf(dx) + fabsf(dy) + fabsf(dz);
            float d2 = dx * dx + dy * dy + dz * dz;
            m1 = fminf(m1, d1); m2 = fminf(m2, d2);
        }
        o1[idx] = m1; o2[idx] = m2;
    }
}

// ============ K2 finale: hungarian (8) + chamfer reduce (104) + rep reduce (1) ============
__global__ void finale_kernel(const float* __restrict__ pred_logits,
                              float* __restrict__ ws, float* __restrict__ out) {
    const int blk = blockIdx.x;
    const int tid = threadIdx.x;

    float* cham = ws;
    float* ns   = ws + 1920;
    float* dd   = ws + 3840;
    float* cost = ws + 5760;
    float* cnt  = ws + 7680;
    float* acc  = ws + 7776;
    int*   done = (int*)(ws + 7782);
    float* rep_part = ws + 7808;
    float* pmA1 = ws + 8192;
    float* pmA2 = ws + 90112;
    float* pmB1 = ws + 172032;
    float* pmB2 = ws + 253952;

    if (blk < 8) {
        // ---- wave-parallel transposed rectangular JV + fused cls/param/pvd ----
        // (equivalent to reference's pad-to-square 20x20; absmax 0.0 in R2-R5)
        if (tid >= 64) return;
        const int b = blk;
        const int t = tid;
        __shared__ double hsm[Pn * Qn];
        for (int k = t; k < Qn * Pn; k += 64)
            hsm[(k % Pn) * Qn + (k / Pn)] = (double)cost[b * Qn * Pn + k];
        // single-wave LDS use: compiler inserts lgkmcnt before dependent reads

        const int col = t;
        const bool isCol = (col >= 1 && col <= Qn);
        double v = 0.0, u = 0.0, minv = 0.0;
        int way = 0, p = 0;

        for (int i = 1; i <= Pn; ++i) {
            const int p0 = i;
            minv = 1e18;
            bool used = false;
            bool rowInPath = false;
            int j0 = 0;
            while (true) {
                if (col == j0) used = true;
                int i0 = (j0 == 0) ? p0 : __shfl(p, j0);
                if (t == i0) rowInPath = true;
                double u_i0 = __shfl(u, i0);
                double mv = 1e18;
                if (isCol && !used) {
                    double cur = hsm[(i0 - 1) * Qn + (col - 1)] - u_i0 - v;
                    if (cur < minv) { minv = cur; way = j0; }
                    mv = minv;
                }
                double bv = mv; int bj = col;
#pragma unroll
                for (int off = 16; off > 0; off >>= 1) {
                    double ov = __shfl_down(bv, off);
                    int    oj = __shfl_down(bj, off);
                    if (ov < bv) { bv = ov; bj = oj; }
                }
                double delta = __shfl(bv, 0);
                int    j1    = __shfl(bj, 0);
                if (used || col == 0) v -= delta;
                else if (isCol)       minv -= delta;
                if (rowInPath)        u += delta;
                j0 = j1;
                int pj0 = __shfl(p, j0);
                if (pj0 == 0) break;
            }
            while (j0 != 0) {
                int wj = __shfl(way, j0);
                int pw = (wj == 0) ? p0 : __shfl(p, wj);
                if (col == j0) p = pw;
                j0 = wj;
            }
        }

        float cls = 0.f, par = 0.f, pvd = 0.f;
        if (isCol) {
            float x = pred_logits[b * Qn + (col - 1)];
            float tgt = (p > 0) ? 1.f : 0.f;
            cls = fmaxf(x, 0.f) - x * tgt + log1pf(expf(-fabsf(x)));
            if (p > 0) {
                int idx = (b * Qn + (col - 1)) * Pn + (p - 1);
                par = ns[idx] + dd[idx];
                pvd = (cnt[b * Pn + (p - 1)] > 0.f) ? cham[idx] : 0.f;
            }
        }
        for (int off = 32; off > 0; off >>= 1) {
            cls += __shfl_down(cls, off);
            par += __shfl_down(par, off);
            pvd += __shfl_down(pvd, off);
        }
        if (t == 0) {
            atomicAdd(&acc[0], cls / (float)(Bn * Qn));
            atomicAdd(&acc[1], par / (float)(Bn * Pn));
            atomicAdd(&acc[2], pvd / (float)(Bn * Pn));
            contribute(acc, done, out);
        }
        return;
    }

    // ---- chamfer reduce (blocks 8..111) + repulsion reduce (block 112) ----
    __shared__ float s1[256], s2[256];
    const int cblk = blk - 8;
    float c1 = 0.f, c2 = 0.f;
    if (cblk < 40) {
        int idx = cblk * 256 + tid;
        float m1 = 3.4e38f, m2 = 3.4e38f;
#pragma unroll
        for (int s = 0; s < SA; ++s) {
            m1 = fminf(m1, pmA1[s * (Bn * Mn) + idx]);
            m2 = fminf(m2, pmA2[s * (Bn * Mn) + idx]);
        }
        c1 = m1 * (0.5f / (float)(Bn * Mn));
        c2 = m2 * (0.5f / (float)(Bn * Mn));
    } else if (cblk < 104) {
        int idx = (cblk - 40) * 256 + tid;
        float m1 = 3.4e38f, m2 = 3.4e38f;
#pragma unroll
        for (int s = 0; s < SB; ++s) {
            m1 = fminf(m1, pmB1[s * (Bn * Gn) + idx]);
            m2 = fminf(m2, pmB2[s * (Bn * Gn) + idx]);
        }
        c1 = m1 * (0.5f / (float)(Bn * Gn));
        c2 = m2 * (0.5f / (float)(Bn * Gn));
    } else {
        c1 = (tid < Bn * Qn) ? rep_part[tid] / (float)(Bn * Qn) : 0.f;
    }
    s1[tid] = c1; s2[tid] = c2;
    __syncthreads();
    for (int off = 128; off > 0; off >>= 1) {
        if (tid < off) { s1[tid] += s1[tid + off]; s2[tid] += s2[tid + off]; }
        __syncthreads();
    }
    if (tid == 0) {
        if (cblk < 104) {
            atomicAdd(&acc[4], s1[0]);
            atomicAdd(&acc[5], s2[0]);
        } else {
            atomicAdd(&acc[3], s1[0]);
        }
        contribute(acc, done, out);
    }
}

extern "C" void kernel_launch(void* const* d_in, const int* in_sizes, int n_in,
                              void* d_out, int out_size, void* d_ws, size_t ws_size,
                              hipStream_t stream) {
    const float* pred_logits    = (const float*)d_in[0];
    const float* pred_normals   = (const float*)d_in[1];
    const float* pred_distances = (const float*)d_in[2];
    const float* gt_normals     = (const float*)d_in[3];
    const float* gt_distances   = (const float*)d_in[4];
    const int*   gt_masks       = (const int*)d_in[5];
    const float* points         = (const float*)d_in[6];
    const float* recon          = (const float*)d_in[7];
    const float* gt             = (const float*)d_in[8];
    // d_in[9] (gt_index) is unused by the reference.

    mega1_kernel<<<840, 256, 0, stream>>>(pred_normals, pred_distances, gt_normals,
                                          gt_distances, points, gt_masks, recon, gt,
                                          (float*)d_ws);
    finale_kernel<<<113, 256, 0, stream>>>(pred_logits, (float*)d_ws, (float*)d_out);
}